// Round 3
// baseline (920.149 us; speedup 1.0000x reference)
//
#include <hip/hip_runtime.h>

// Problem constants
#define NN 16384
// ws (bf16) region offsets, in elements
#define OFF_EWT 0
#define OFF_WQT 4096
#define OFF_WKT 36864
#define OFF_WVT 69632
#define OFF_AFT 102400
#define OFF_W1T 135168
#define OFF_W2T 266240
#define OFF_F2N 397312
#define TOTAL_W 413696

typedef __attribute__((ext_vector_type(8))) short bf16x8;
typedef __attribute__((ext_vector_type(4))) short bf16x4;
typedef __attribute__((ext_vector_type(4))) float f32x4;

static __device__ __forceinline__ short f2bf(float f) {
  unsigned u = __builtin_bit_cast(unsigned, f);
  u += 0x7fffu + ((u >> 16) & 1u);           // RNE
  return (short)(u >> 16);
}
static __device__ __forceinline__ float bf2f(short h) {
  unsigned u = ((unsigned)(unsigned short)h) << 16;
  return __builtin_bit_cast(float, u);
}
static __device__ __forceinline__ float gelu_f(float x) {
  float e = __expf(1.5957691216057308f * (x + 0.044715f * x * x * x));
  return x - x / (e + 1.0f);
}
static __device__ __forceinline__ f32x4 mfma16(bf16x8 a, bf16x8 b, f32x4 c) {
  return __builtin_amdgcn_mfma_f32_16x16x32_bf16(a, b, c, 0, 0, 0);
}
// XOR bank swizzle v2: spreads the 4 lq-groups into distinct bank quartets
#define SWZM(row) (((((row) & 7) << 4)) ^ ((((row) >> 3) & 3) << 5))
static __device__ __forceinline__ int swzb(int row, int col) {
  return row * 256 + ((col * 2) ^ SWZM(row));
}
static __device__ __forceinline__ bf16x8 tile_ld8(const short* base, int row, int col) {
  return *(const bf16x8*)((const char*)base + swzb(row, col));
}
static __device__ __forceinline__ void tile_st16(short* base, int row, int col, short v) {
  *(short*)((char*)base + swzb(row, col)) = v;
}
// async stage: [128][stride] global (row-major) -> 32KB swizzled LDS tile.
static __device__ __forceinline__ void stage_async(short* dst, const short* src, int stride,
                                                   int w, int lane) {
  #pragma unroll
  for (int it = 0; it < 8; ++it) {
    int dbase = (it * 4 + w) * 1024;          // wave-uniform dest byte offset
    int d = dbase + lane * 16;
    int row = d >> 8;
    int scolb = (d & 255) ^ SWZM(row);        // source byte-in-row (involution)
    const short* sp = src + row * stride + (scolb >> 1);
    __builtin_amdgcn_global_load_lds(
        (const __attribute__((address_space(1))) unsigned int*)sp,
        (__attribute__((address_space(3))) unsigned int*)((char*)dst + dbase),
        16, 0, 0);
  }
}

#define LD_FA(SRC)                                                        \
  _Pragma("unroll") for (int _s = 0; _s < 4; ++_s)                        \
      fA[_s] = tile_ld8((SRC), li, _s * 32 + lq * 8);

#define ST_TILE(T, ACC)                                                   \
  _Pragma("unroll") for (int _c = 0; _c < 8; ++_c)                        \
    _Pragma("unroll") for (int _r = 0; _r < 4; ++_r)                      \
      tile_st16((T), lq * 4 + _r, _c * 16 + li, f2bf((ACC)[_c][_r]));

#define LAYER_NORM(A, GP, BP) do {                                        \
    float _gg[8], _bb[8];                                                 \
    _Pragma("unroll") for (int _c = 0; _c < 8; ++_c) {                    \
      _gg[_c] = (GP)[_c * 16 + li]; _bb[_c] = (BP)[_c * 16 + li]; }       \
    _Pragma("unroll") for (int _r = 0; _r < 4; ++_r) {                    \
      float _s1 = 0.f, _s2 = 0.f;                                         \
      _Pragma("unroll") for (int _c = 0; _c < 8; ++_c) {                  \
        float _v = (A)[_c][_r]; _s1 += _v; _s2 += _v * _v; }              \
      _Pragma("unroll") for (int _m = 1; _m <= 8; _m <<= 1) {             \
        _s1 += __shfl_xor(_s1, _m, 64); _s2 += __shfl_xor(_s2, _m, 64); } \
      float _mean = _s1 * (1.f / 128.f);                                  \
      float _var = _s2 * (1.f / 128.f) - _mean * _mean;                   \
      float _rstd = rsqrtf(_var + 1e-5f);                                 \
      _Pragma("unroll") for (int _c = 0; _c < 8; ++_c)                    \
        (A)[_c][_r] = ((A)[_c][_r] - _mean) * _rstd * _gg[_c] + _bb[_c];  \
    }                                                                     \
  } while (0)

// ---- prep: transpose + fp32->bf16 all weight matrices into ws ----
__global__ void prep_kernel(const float* __restrict__ ew, const float* __restrict__ wq,
                            const float* __restrict__ wk, const float* __restrict__ wv,
                            const float* __restrict__ afc, const float* __restrict__ w1,
                            const float* __restrict__ w2, const float* __restrict__ f2n,
                            short* __restrict__ wsb) {
  int tt = blockIdx.x * 256 + threadIdx.x;
  if (tt >= TOTAL_W) return;
  short v;
  if (tt < OFF_WQT) {                       // EWT [128][32] <- ew [32][128]
    int u = tt; int row = u >> 5, colr = u & 31;
    v = f2bf(ew[colr * 128 + row]);
  } else if (tt < OFF_WKT) {                // WQT [2][128][128]
    int u = tt - OFF_WQT; int i = u >> 14; u &= 16383; int row = u >> 7, colr = u & 127;
    v = f2bf(wq[i * 16384 + colr * 128 + row]);
  } else if (tt < OFF_WVT) {
    int u = tt - OFF_WKT; int i = u >> 14; u &= 16383; int row = u >> 7, colr = u & 127;
    v = f2bf(wk[i * 16384 + colr * 128 + row]);
  } else if (tt < OFF_AFT) {
    int u = tt - OFF_WVT; int i = u >> 14; u &= 16383; int row = u >> 7, colr = u & 127;
    v = f2bf(wv[i * 16384 + colr * 128 + row]);
  } else if (tt < OFF_W1T) {                // AFT [2][128][128]
    int u = tt - OFF_AFT; int i = u >> 14; u &= 16383; int row = u >> 7, colr = u & 127;
    v = f2bf(afc[i * 16384 + colr * 128 + row]);
  } else if (tt < OFF_W2T) {                // W1T [2][512][128] <- w1 [2][128][512]
    int u = tt - OFF_W1T; int i = u >> 16; u &= 65535; int row = u >> 7, colr = u & 127;
    v = f2bf(w1[i * 65536 + colr * 512 + row]);
  } else if (tt < OFF_F2N) {                // W2T [2][128][512] <- w2 [2][512][128]
    int u = tt - OFF_W2T; int i = u >> 16; u &= 65535; int row = u >> 9, colr = u & 511;
    v = f2bf(w2[i * 65536 + colr * 128 + row]);
  } else {                                  // F2N [128][128] <- f2n [128][128]
    int u = tt - OFF_F2N; int row = u >> 7, colr = u & 127;
    v = f2bf(f2n[colr * 128 + row]);
  }
  wsb[tt] = v;
}

// ---- fused main kernel: 1 wave = 1 node, 4 waves/WG ----
__global__ __launch_bounds__(256, 2) void fused_kernel(
    const float* __restrict__ node_h, const int* __restrict__ src_idx,
    const float* __restrict__ edge_feat, const float* __restrict__ t_arr,
    const float* __restrict__ t_now, const float* __restrict__ edge_fc_b,
    const float* __restrict__ basis_freq, const float* __restrict__ phase,
    const float* __restrict__ attn_fc_b, const float* __restrict__ attn_ln_g,
    const float* __restrict__ attn_ln_b, const float* __restrict__ ffn_b1,
    const float* __restrict__ ffn_b2, const float* __restrict__ ffn_ln_g,
    const float* __restrict__ ffn_ln_b, const float* __restrict__ f2n_b,
    const float* __restrict__ fin_g, const float* __restrict__ fin_b,
    const short* __restrict__ wsb, float* __restrict__ out) {
  __shared__ __align__(16) short lds_w[16384];     // 32KB weight stage (Vt+O scratch during attn)
  __shared__ __align__(16) short lds_qk[4][4096];  // per-node Q,K tiles / f transpose scratch

  const int tid = (int)threadIdx.x;
  const int w = tid >> 6, lane = tid & 63, li = lane & 15, lq = lane >> 4;
  const int n = (int)blockIdx.x * 4 + w;
  short* myQ = lds_qk[w];
  short* myK = lds_qk[w] + 2048;
  short* myVt = lds_w + w * 4096;                  // [128][16] bf16 (attn only)
  short* myOs = lds_w + w * 4096 + 2048;           // O scratch tile (attn only)
  const f32x4 F0 = {0.f, 0.f, 0.f, 0.f};
  const bf16x8 B0 = {0, 0, 0, 0, 0, 0, 0, 0};

  const float tnow = t_now[0];

  // acc[8] carries the exact fp32 row-state f for this node at all times.
  f32x4 acc[8];
  // ================= message phase =================
  {
    const float* ef = edge_feat + ((size_t)(n * 16 + li)) * 32 + lq * 8;
    f32x4 e0 = *(const f32x4*)(ef);
    f32x4 e1 = *(const f32x4*)(ef + 4);
    bf16x8 ea;
    #pragma unroll
    for (int j = 0; j < 4; ++j) { ea[j] = f2bf(e0[j]); ea[j + 4] = f2bf(e1[j]); }
    const short* ewt = wsb + OFF_EWT;
    #pragma unroll
    for (int c = 0; c < 8; ++c) {
      bf16x8 eb = *(const bf16x8*)(ewt + (c * 16 + li) * 32 + lq * 8);
      acc[c] = mfma16(ea, eb, F0);
    }
  }
  {
    float bfq[8], phs[8], ebs[8];
    #pragma unroll
    for (int c = 0; c < 8; ++c) {
      int col = c * 16 + li;
      bfq[c] = basis_freq[col]; phs[c] = phase[col]; ebs[c] = edge_fc_b[col];
    }
    #pragma unroll
    for (int r = 0; r < 4; ++r) {
      int m = lq * 4 + r;
      int sidx = src_idx[n * 16 + m];
      float dt = tnow - t_arr[n * 16 + m];
      const float* nh = node_h + (size_t)sidx * 128;
      #pragma unroll
      for (int c = 0; c < 8; ++c) {
        int col = c * 16 + li;
        float x = gelu_f(acc[c][r] + ebs[c]);
        x += nh[col];
        x += __cosf(dt * bfq[c] + phs[c]);
        acc[c][r] = x;
      }
    }
  }
  ST_TILE(myQ, acc);   // f tile -> transpose scratch

  bf16x8 fA[4];

  // ================= transformer layers =================
  for (int il = 0; il < 2; ++il) {
    const short* WQT = wsb + OFF_WQT + il * 16384;
    const short* WKT = wsb + OFF_WKT + il * 16384;
    const short* WVT = wsb + OFF_WVT + il * 16384;
    const short* AFT = wsb + OFF_AFT + il * 16384;
    const short* W1T = wsb + OFF_W1T + il * 65536;
    const short* W2T = wsb + OFF_W2T + il * 65536;

    // ---- Q (myQ currently holds the f tile; read fA first, then overwrite) ----
    __syncthreads();
    stage_async(lds_w, WQT, 128, w, lane);
    __syncthreads();
    LD_FA(myQ);
    #pragma unroll
    for (int cg = 0; cg < 2; ++cg) {
      f32x4 g[4];
      #pragma unroll
      for (int j = 0; j < 4; ++j) g[j] = F0;
      #pragma unroll
      for (int s = 0; s < 4; ++s)
        #pragma unroll
        for (int j = 0; j < 4; ++j)
          g[j] = mfma16(fA[s], tile_ld8(lds_w, (cg * 4 + j) * 16 + li, s * 32 + lq * 8), g[j]);
      #pragma unroll
      for (int j = 0; j < 4; ++j)
        #pragma unroll
        for (int r = 0; r < 4; ++r)
          tile_st16(myQ, lq * 4 + r, (cg * 4 + j) * 16 + li, f2bf(g[j][r]));
    }
    // ---- K ----
    __syncthreads();
    stage_async(lds_w, WKT, 128, w, lane);
    __syncthreads();
    #pragma unroll
    for (int cg = 0; cg < 2; ++cg) {
      f32x4 g[4];
      #pragma unroll
      for (int j = 0; j < 4; ++j) g[j] = F0;
      #pragma unroll
      for (int s = 0; s < 4; ++s)
        #pragma unroll
        for (int j = 0; j < 4; ++j)
          g[j] = mfma16(fA[s], tile_ld8(lds_w, (cg * 4 + j) * 16 + li, s * 32 + lq * 8), g[j]);
      #pragma unroll
      for (int j = 0; j < 4; ++j)
        #pragma unroll
        for (int r = 0; r < 4; ++r)
          tile_st16(myK, lq * 4 + r, (cg * 4 + j) * 16 + li, f2bf(g[j][r]));
    }
    // ---- V (hold all 8 cols in regs until post-sync: Vt lives in lds_w) ----
    __syncthreads();
    stage_async(lds_w, WVT, 128, w, lane);
    __syncthreads();
    {
      f32x4 vacc[8];
      #pragma unroll
      for (int c = 0; c < 8; ++c) vacc[c] = F0;
      #pragma unroll
      for (int s = 0; s < 4; ++s)
        #pragma unroll
        for (int c = 0; c < 8; ++c)
          vacc[c] = mfma16(fA[s], tile_ld8(lds_w, c * 16 + li, s * 32 + lq * 8), vacc[c]);
      __syncthreads();  // all waves done reading WVT before Vt overwrites lds_w
      #pragma unroll
      for (int c = 0; c < 8; ++c) {
        bf16x4 pk;
        #pragma unroll
        for (int r = 0; r < 4; ++r) pk[r] = f2bf(vacc[c][r]);
        *(bf16x4*)(myVt + (c * 16 + li) * 16 + lq * 4) = pk;  // Vt[dv][k], b64 packed
      }
    }

    // ---- attention (wave-local) ----
    #pragma unroll
    for (int h = 0; h < 8; ++h) {
      bf16x8 ka = B0, qa = B0;
      if (lq < 2) {
        ka = tile_ld8(myK, li, h * 16 + lq * 8);
        qa = tile_ld8(myQ, li, h * 16 + lq * 8);
      }
      f32x4 st = mfma16(ka, qa, F0);  // S^T: row k=lq*4+r, col q=li
      float p[4]; float mx = -1e30f;
      #pragma unroll
      for (int r = 0; r < 4; ++r) { p[r] = st[r] * 0.25f; mx = fmaxf(mx, p[r]); }
      mx = fmaxf(mx, __shfl_xor(mx, 16, 64));
      mx = fmaxf(mx, __shfl_xor(mx, 32, 64));
      float sum = 0.f;
      #pragma unroll
      for (int r = 0; r < 4; ++r) { p[r] = __expf(p[r] - mx); sum += p[r]; }
      sum += __shfl_xor(sum, 16, 64);
      sum += __shfl_xor(sum, 32, 64);
      float inv = 1.0f / sum;
      #pragma unroll
      for (int r = 0; r < 4; ++r) p[r] *= inv;
      bf16x8 pa;
      #pragma unroll
      for (int j = 0; j < 8; ++j) {
        float v = __shfl(p[j & 3], li + 16 * (2 * lq + (j >> 2)), 64);
        pa[j] = (lq < 2) ? f2bf(v) : (short)0;
      }
      bf16x8 vb = B0;
      if (lq < 2) vb = *(const bf16x8*)(myVt + (h * 16 + li) * 16 + lq * 8);
      f32x4 o = mfma16(pa, vb, F0);   // O: row q=lq*4+r, col dv=li (head h)
      #pragma unroll
      for (int r = 0; r < 4; ++r)
        tile_st16(myOs, lq * 4 + r, h * 16 + li, f2bf(o[r]));
    }
    bf16x8 oa[4];
    #pragma unroll
    for (int s = 0; s < 4; ++s) oa[s] = tile_ld8(myOs, li, s * 32 + lq * 8);

    // ---- attn_fc + residual(from acc) + LN ----
    __syncthreads();
    stage_async(lds_w, AFT, 128, w, lane);
    __syncthreads();
    #pragma unroll
    for (int c = 0; c < 8; ++c) {
      float bias = attn_fc_b[il * 128 + c * 16 + li];
      #pragma unroll
      for (int r = 0; r < 4; ++r) acc[c][r] += bias;   // C-in preload: f + bias
    }
    #pragma unroll
    for (int s = 0; s < 4; ++s)
      #pragma unroll
      for (int c = 0; c < 8; ++c)
        acc[c] = mfma16(oa[s], tile_ld8(lds_w, c * 16 + li, s * 32 + lq * 8), acc[c]);
    LAYER_NORM(acc, attn_ln_g + il * 128, attn_ln_b + il * 128);
    ST_TILE(myQ, acc);
    LD_FA(myQ);

    // ---- FFN (fused w1+relu+w2 over 4 col-tiles; acc = b2 + f, accumulates W2) ----
    #pragma unroll
    for (int c = 0; c < 8; ++c) {
      float b2 = ffn_b2[il * 128 + c * 16 + li];
      #pragma unroll
      for (int r = 0; r < 4; ++r) acc[c][r] += b2;
    }
    for (int ct = 0; ct < 4; ++ct) {
      __syncthreads();
      stage_async(lds_w, W1T + ct * 16384, 128, w, lane);
      __syncthreads();
      #pragma unroll
      for (int cg = 0; cg < 2; ++cg) {
        f32x4 g[4];
        #pragma unroll
        for (int j = 0; j < 4; ++j) g[j] = F0;
        #pragma unroll
        for (int s = 0; s < 4; ++s)
          #pragma unroll
          for (int j = 0; j < 4; ++j)
            g[j] = mfma16(fA[s], tile_ld8(lds_w, (cg * 4 + j) * 16 + li, s * 32 + lq * 8), g[j]);
        #pragma unroll
        for (int j = 0; j < 4; ++j) {
          float b1 = ffn_b1[il * 512 + ct * 128 + (cg * 4 + j) * 16 + li];
          #pragma unroll
          for (int r = 0; r < 4; ++r)
            tile_st16(myK, lq * 4 + r, (cg * 4 + j) * 16 + li, f2bf(fmaxf(g[j][r] + b1, 0.f)));
        }
      }
      bf16x8 ha[4];
      #pragma unroll
      for (int s = 0; s < 4; ++s) ha[s] = tile_ld8(myK, li, s * 32 + lq * 8);
      __syncthreads();
      stage_async(lds_w, W2T + ct * 128, 512, w, lane);
      __syncthreads();
      #pragma unroll
      for (int s = 0; s < 4; ++s)
        #pragma unroll
        for (int c = 0; c < 8; ++c)
          acc[c] = mfma16(ha[s], tile_ld8(lds_w, c * 16 + li, s * 32 + lq * 8), acc[c]);
    }
    LAYER_NORM(acc, ffn_ln_g + il * 128, ffn_ln_b + il * 128);
    ST_TILE(myQ, acc);   // f tile for next layer's LD_FA
  }

  // ================= pooling + fea2node + final LN =================
  float pc[8];
  #pragma unroll
  for (int c = 0; c < 8; ++c) {
    float s = acc[c][0] + acc[c][1] + acc[c][2] + acc[c][3];
    s += __shfl_xor(s, 16, 64);
    s += __shfl_xor(s, 32, 64);
    pc[c] = s * (1.f / 16.f);
  }
  float* ps = (float*)myK;  // 128 floats scratch (K dead)
  if (lq == 0) {
    #pragma unroll
    for (int c = 0; c < 8; ++c) ps[c * 16 + li] = pc[c];
  }
  const short* F2NT = wsb + OFF_F2N;
  float yv[2];
  #pragma unroll
  for (int half = 0; half < 2; ++half) {
    int col = half * 64 + lane;
    float dot = 0.f;
    for (int d0 = 0; d0 < 128; d0 += 8) {
      bf16x8 wv8 = *(const bf16x8*)(F2NT + col * 128 + d0);
      f32x4 p0 = *(const f32x4*)(ps + d0);
      f32x4 p1 = *(const f32x4*)(ps + d0 + 4);
      dot += p0[0] * bf2f(wv8[0]) + p0[1] * bf2f(wv8[1]) + p0[2] * bf2f(wv8[2]) + p0[3] * bf2f(wv8[3]);
      dot += p1[0] * bf2f(wv8[4]) + p1[1] * bf2f(wv8[5]) + p1[2] * bf2f(wv8[6]) + p1[3] * bf2f(wv8[7]);
    }
    yv[half] = gelu_f(dot + f2n_b[col]) + node_h[(size_t)n * 128 + col];
  }
  float s1 = yv[0] + yv[1], s2 = yv[0] * yv[0] + yv[1] * yv[1];
  #pragma unroll
  for (int m = 1; m <= 32; m <<= 1) { s1 += __shfl_xor(s1, m, 64); s2 += __shfl_xor(s2, m, 64); }
  float mean = s1 * (1.f / 128.f);
  float var = s2 * (1.f / 128.f) - mean * mean;
  float rstd = rsqrtf(var + 1e-5f);
  #pragma unroll
  for (int half = 0; half < 2; ++half) {
    int col = half * 64 + lane;
    out[(size_t)n * 128 + col] = (yv[half] - mean) * rstd * fin_g[col] + fin_b[col];
  }
}

extern "C" void kernel_launch(void* const* d_in, const int* in_sizes, int n_in,
                              void* d_out, int out_size, void* d_ws, size_t ws_size,
                              hipStream_t stream) {
  const float* node_h    = (const float*)d_in[0];
  const int*   src_idx   = (const int*)d_in[1];
  const float* edge_feat = (const float*)d_in[2];
  const float* t_arr     = (const float*)d_in[3];
  const float* t_now     = (const float*)d_in[4];
  const float* edge_fc_w = (const float*)d_in[5];
  const float* edge_fc_b = (const float*)d_in[6];
  const float* basis_frq = (const float*)d_in[7];
  const float* phase     = (const float*)d_in[8];
  const float* wq        = (const float*)d_in[9];
  const float* wk        = (const float*)d_in[10];
  const float* wv        = (const float*)d_in[11];
  const float* attn_fc_w = (const float*)d_in[12];
  const float* attn_fc_b = (const float*)d_in[13];
  const float* attn_ln_g = (const float*)d_in[14];
  const float* attn_ln_b = (const float*)d_in[15];
  const float* ffn_w1    = (const float*)d_in[16];
  const float* ffn_b1    = (const float*)d_in[17];
  const float* ffn_w2    = (const float*)d_in[18];
  const float* ffn_b2    = (const float*)d_in[19];
  const float* ffn_ln_g  = (const float*)d_in[20];
  const float* ffn_ln_b  = (const float*)d_in[21];
  const float* f2n_w     = (const float*)d_in[22];
  const float* f2n_b     = (const float*)d_in[23];
  const float* fin_g     = (const float*)d_in[24];
  const float* fin_b     = (const float*)d_in[25];
  short* wsb = (short*)d_ws;

  prep_kernel<<<(TOTAL_W + 255) / 256, 256, 0, stream>>>(
      edge_fc_w, wq, wk, wv, attn_fc_w, ffn_w1, ffn_w2, f2n_w, wsb);
  fused_kernel<<<NN / 4, 256, 0, stream>>>(
      node_h, src_idx, edge_feat, t_arr, t_now, edge_fc_b, basis_frq, phase,
      attn_fc_b, attn_ln_g, attn_ln_b, ffn_b1, ffn_b2, ffn_ln_g, ffn_ln_b,
      f2n_b, fin_g, fin_b, wsb, (float*)d_out);
}

// Round 6
// 758.198 us; speedup vs baseline: 1.2136x; 1.2136x over previous
//
#include <hip/hip_runtime.h>

// Problem constants
#define NN 16384
// ws (bf16) region offsets, in elements
#define OFF_EWT 0
#define OFF_WQT 4096
#define OFF_WKT 36864
#define OFF_WVT 69632
#define OFF_AFT 102400
#define OFF_W1T 135168
#define OFF_W2T 266240
#define OFF_F2N 397312
#define TOTAL_W 413696

typedef __attribute__((ext_vector_type(8))) short bf16x8;
typedef __attribute__((ext_vector_type(4))) short bf16x4;
typedef __attribute__((ext_vector_type(4))) float f32x4;

static __device__ __forceinline__ short f2bf(float f) {
  unsigned u = __builtin_bit_cast(unsigned, f);
  u += 0x7fffu + ((u >> 16) & 1u);           // RNE
  return (short)(u >> 16);
}
static __device__ __forceinline__ float bf2f(short h) {
  unsigned u = ((unsigned)(unsigned short)h) << 16;
  return __builtin_bit_cast(float, u);
}
static __device__ __forceinline__ float gelu_f(float x) {
  float e = __expf(1.5957691216057308f * (x + 0.044715f * x * x * x));
  return x - x / (e + 1.0f);
}
static __device__ __forceinline__ f32x4 mfma16(bf16x8 a, bf16x8 b, f32x4 c) {
  return __builtin_amdgcn_mfma_f32_16x16x32_bf16(a, b, c, 0, 0, 0);
}
// XOR bank swizzle
#define SWZM(row) (((((row) & 7) << 4)) ^ ((((row) >> 3) & 3) << 5))
static __device__ __forceinline__ int swzb(int row, int col) {
  return row * 256 + ((col * 2) ^ SWZM(row));
}
static __device__ __forceinline__ bf16x8 tile_ld8(const short* base, int row, int col) {
  return *(const bf16x8*)((const char*)base + swzb(row, col));
}
static __device__ __forceinline__ void tile_st16(short* base, int row, int col, short v) {
  *(short*)((char*)base + swzb(row, col)) = v;
}
// async half-stage: 64 rows x 128 cols bf16 (16KB) -> swizzled LDS buffer.
// 4 waves x 4 global_load_lds(16B x 64 lanes); dest linear, source pre-swizzled.
static __device__ __forceinline__ void stage_w(short* dst, const short* src, int stride,
                                               int w, int lane) {
  #pragma unroll
  for (int it = 0; it < 4; ++it) {
    int dbase = (it * 4 + w) * 1024;
    int d = dbase + lane * 16;
    int row = d >> 8;                         // 0..63 local row
    int scolb = (d & 255) ^ SWZM(row);        // source byte-in-row (involution)
    const short* sp = src + row * stride + (scolb >> 1);
    __builtin_amdgcn_global_load_lds(
        (const __attribute__((address_space(1))) unsigned int*)sp,
        (__attribute__((address_space(3))) unsigned int*)((char*)dst + dbase),
        16, 0, 0);
  }
}

#define LDS_FENCE() do {                                       \
    asm volatile("s_waitcnt lgkmcnt(0)" ::: "memory");         \
    __builtin_amdgcn_sched_barrier(0);                         \
  } while (0)

#define ISSUE(SRC, STRIDE) stage_w(bn, (SRC), (STRIDE), w, lane)
#define ENDSTEP() do {                                         \
    __syncthreads();                                           \
    short* _t = bc; bc = bn; bn = _t;                          \
  } while (0)

#define LD_FA(SRC)                                                        \
  _Pragma("unroll") for (int _s = 0; _s < 4; ++_s)                        \
      fA[_s] = tile_ld8((SRC), li, _s * 32 + lq * 8);

#define ST_TILE(T, ACC)                                                   \
  _Pragma("unroll") for (int _c = 0; _c < 8; ++_c)                        \
    _Pragma("unroll") for (int _r = 0; _r < 4; ++_r)                      \
      tile_st16((T), lq * 4 + _r, _c * 16 + li, f2bf((ACC)[_c][_r]));

// 16-MFMA half-projection from a staged 64-row buffer (4 output col-tiles)
#define PROJ4(AR, BB)                                                     \
    f32x4 g0 = F0, g1 = F0, g2 = F0, g3 = F0;                             \
    _Pragma("unroll") for (int _s = 0; _s < 4; ++_s) {                    \
      int _sc = _s * 32 + lq * 8;                                         \
      g0 = mfma16(AR[_s], tile_ld8((BB), 0 + li, _sc), g0);               \
      g1 = mfma16(AR[_s], tile_ld8((BB), 16 + li, _sc), g1);              \
      g2 = mfma16(AR[_s], tile_ld8((BB), 32 + li, _sc), g2);              \
      g3 = mfma16(AR[_s], tile_ld8((BB), 48 + li, _sc), g3);              \
    }

#define ST4(DST, CB)                                                      \
    _Pragma("unroll") for (int _r = 0; _r < 4; ++_r) {                    \
      tile_st16((DST), lq * 4 + _r, ((CB) + 0) * 16 + li, f2bf(g0[_r])); \
      tile_st16((DST), lq * 4 + _r, ((CB) + 1) * 16 + li, f2bf(g1[_r])); \
      tile_st16((DST), lq * 4 + _r, ((CB) + 2) * 16 + li, f2bf(g2[_r])); \
      tile_st16((DST), lq * 4 + _r, ((CB) + 3) * 16 + li, f2bf(g3[_r])); \
    }

// accumulate acc[CB..CB+3] += A * staged-half
#define ACC4(AR, CB, BB)                                                  \
    _Pragma("unroll") for (int _s = 0; _s < 4; ++_s) {                    \
      int _sc = _s * 32 + lq * 8;                                         \
      acc[(CB) + 0] = mfma16(AR[_s], tile_ld8((BB), 0 + li, _sc), acc[(CB) + 0]);  \
      acc[(CB) + 1] = mfma16(AR[_s], tile_ld8((BB), 16 + li, _sc), acc[(CB) + 1]); \
      acc[(CB) + 2] = mfma16(AR[_s], tile_ld8((BB), 32 + li, _sc), acc[(CB) + 2]); \
      acc[(CB) + 3] = mfma16(AR[_s], tile_ld8((BB), 48 + li, _sc), acc[(CB) + 3]); \
    }

#define LAYER_NORM(A, GP, BP) do {                                        \
    float _gg[8], _bb[8];                                                 \
    _Pragma("unroll") for (int _c = 0; _c < 8; ++_c) {                    \
      _gg[_c] = (GP)[_c * 16 + li]; _bb[_c] = (BP)[_c * 16 + li]; }       \
    _Pragma("unroll") for (int _r = 0; _r < 4; ++_r) {                    \
      float _s1 = 0.f, _s2 = 0.f;                                         \
      _Pragma("unroll") for (int _c = 0; _c < 8; ++_c) {                  \
        float _v = (A)[_c][_r]; _s1 += _v; _s2 += _v * _v; }              \
      _Pragma("unroll") for (int _m = 1; _m <= 8; _m <<= 1) {             \
        _s1 += __shfl_xor(_s1, _m, 64); _s2 += __shfl_xor(_s2, _m, 64); } \
      float _mean = _s1 * (1.f / 128.f);                                  \
      float _var = _s2 * (1.f / 128.f) - _mean * _mean;                   \
      float _rstd = rsqrtf(_var + 1e-5f);                                 \
      _Pragma("unroll") for (int _c = 0; _c < 8; ++_c)                    \
        (A)[_c][_r] = ((A)[_c][_r] - _mean) * _rstd * _gg[_c] + _bb[_c];  \
    }                                                                     \
  } while (0)

// ---- prep: transpose + fp32->bf16 all weight matrices into ws ----
__global__ void prep_kernel(const float* __restrict__ ew, const float* __restrict__ wq,
                            const float* __restrict__ wk, const float* __restrict__ wv,
                            const float* __restrict__ afc, const float* __restrict__ w1,
                            const float* __restrict__ w2, const float* __restrict__ f2n,
                            short* __restrict__ wsb) {
  int tt = blockIdx.x * 256 + threadIdx.x;
  if (tt >= TOTAL_W) return;
  short v;
  if (tt < OFF_WQT) {                       // EWT [128][32] <- ew [32][128]
    int u = tt; int row = u >> 5, colr = u & 31;
    v = f2bf(ew[colr * 128 + row]);
  } else if (tt < OFF_WKT) {                // WQT [2][128][128]
    int u = tt - OFF_WQT; int i = u >> 14; u &= 16383; int row = u >> 7, colr = u & 127;
    v = f2bf(wq[i * 16384 + colr * 128 + row]);
  } else if (tt < OFF_WVT) {
    int u = tt - OFF_WKT; int i = u >> 14; u &= 16383; int row = u >> 7, colr = u & 127;
    v = f2bf(wk[i * 16384 + colr * 128 + row]);
  } else if (tt < OFF_AFT) {
    int u = tt - OFF_WVT; int i = u >> 14; u &= 16383; int row = u >> 7, colr = u & 127;
    v = f2bf(wv[i * 16384 + colr * 128 + row]);
  } else if (tt < OFF_W1T) {                // AFT [2][128][128]
    int u = tt - OFF_AFT; int i = u >> 14; u &= 16383; int row = u >> 7, colr = u & 127;
    v = f2bf(afc[i * 16384 + colr * 128 + row]);
  } else if (tt < OFF_W2T) {                // W1T [2][512][128] <- w1 [2][128][512]
    int u = tt - OFF_W1T; int i = u >> 16; u &= 65535; int row = u >> 7, colr = u & 127;
    v = f2bf(w1[i * 65536 + colr * 512 + row]);
  } else if (tt < OFF_F2N) {                // W2T [2][128][512] <- w2 [2][512][128]
    int u = tt - OFF_W2T; int i = u >> 16; u &= 65535; int row = u >> 9, colr = u & 511;
    v = f2bf(w2[i * 65536 + colr * 128 + row]);
  } else {                                  // F2N [128][128] <- f2n [128][128]
    int u = tt - OFF_F2N; int row = u >> 7, colr = u & 127;
    v = f2bf(f2n[colr * 128 + row]);
  }
  wsb[tt] = v;
}

// ---- fused main kernel: 1 wave = 1 node, 4 waves/WG, issue-early dbuf ----
__global__ __launch_bounds__(256, 2) void fused_kernel(
    const float* __restrict__ node_h, const int* __restrict__ src_idx,
    const float* __restrict__ edge_feat, const float* __restrict__ t_arr,
    const float* __restrict__ t_now, const float* __restrict__ edge_fc_b,
    const float* __restrict__ basis_freq, const float* __restrict__ phase,
    const float* __restrict__ attn_fc_b, const float* __restrict__ attn_ln_g,
    const float* __restrict__ attn_ln_b, const float* __restrict__ ffn_b1,
    const float* __restrict__ ffn_b2, const float* __restrict__ ffn_ln_g,
    const float* __restrict__ ffn_ln_b, const float* __restrict__ f2n_b,
    const float* __restrict__ fin_g, const float* __restrict__ fin_b,
    const short* __restrict__ wsb, float* __restrict__ out) {
  __shared__ __align__(16) short bufs0[8192];      // 16KB weight half A
  __shared__ __align__(16) short bufs1[8192];      // 16KB weight half B
  __shared__ __align__(16) short lds_qk[4][4096];  // per-wave Q(2048)+K(2048)

  const int tid = (int)threadIdx.x;
  const int w = tid >> 6, lane = tid & 63, li = lane & 15, lq = lane >> 4;
  const int n = (int)blockIdx.x * 4 + w;
  short* myQ = lds_qk[w];                          // f / Q / Os tile
  short* myK = lds_qk[w] + 2048;                   // K / Vt / hid tile / pool scratch
  short* bc = bufs0;                               // current staged half
  short* bn = bufs1;                               // next staged half
  const f32x4 F0 = {0.f, 0.f, 0.f, 0.f};
  const bf16x8 B0 = {0, 0, 0, 0, 0, 0, 0, 0};

  // prologue: issue layer-0 WQ h0 before the message phase (latency hidden)
  stage_w(bc, wsb + OFF_WQT, 128, w, lane);

  const float tnow = t_now[0];

  // acc[8] carries the exact fp32 row-state f for this node at all times.
  f32x4 acc[8];
  // ================= message phase =================
  {
    const float* ef = edge_feat + ((size_t)(n * 16 + li)) * 32 + lq * 8;
    f32x4 e0 = *(const f32x4*)(ef);
    f32x4 e1 = *(const f32x4*)(ef + 4);
    bf16x8 ea;
    #pragma unroll
    for (int j = 0; j < 4; ++j) { ea[j] = f2bf(e0[j]); ea[j + 4] = f2bf(e1[j]); }
    const short* ewt = wsb + OFF_EWT;
    #pragma unroll
    for (int c = 0; c < 8; ++c) {
      bf16x8 eb = *(const bf16x8*)(ewt + (c * 16 + li) * 32 + lq * 8);
      acc[c] = mfma16(ea, eb, F0);
    }
  }
  {
    float bfq[8], phs[8], ebs[8];
    #pragma unroll
    for (int c = 0; c < 8; ++c) {
      int col = c * 16 + li;
      bfq[c] = basis_freq[col]; phs[c] = phase[col]; ebs[c] = edge_fc_b[col];
    }
    #pragma unroll
    for (int r = 0; r < 4; ++r) {
      int m = lq * 4 + r;
      int sidx = src_idx[n * 16 + m];
      float dt = tnow - t_arr[n * 16 + m];
      const float* nh = node_h + (size_t)sidx * 128;
      #pragma unroll
      for (int c = 0; c < 8; ++c) {
        int col = c * 16 + li;
        float x = gelu_f(acc[c][r] + ebs[c]);
        x += nh[col];
        x += __cosf(dt * bfq[c] + phs[c]);
        acc[c][r] = x;
      }
    }
  }
  ST_TILE(myQ, acc);   // f tile
  __syncthreads();     // drains prologue stage; f/WQ0 ready

  bf16x8 fA[4];

  // ================= transformer layers (24 pipelined steps each) =================
  for (int il = 0; il < 2; ++il) {
    const short* WQT = wsb + OFF_WQT + il * 16384;
    const short* WKT = wsb + OFF_WKT + il * 16384;
    const short* WVT = wsb + OFF_WVT + il * 16384;
    const short* AFT = wsb + OFF_AFT + il * 16384;
    const short* W1T = wsb + OFF_W1T + il * 65536;
    const short* W2T = wsb + OFF_W2T + il * 65536;
    const short* WQN = wsb + OFF_WQT + ((il == 0) ? 16384 : 0);  // next WQ (dummy on last)

    // s0: WQ h0
    ISSUE(WQT + 8192, 128);
    LD_FA(myQ);                      // read f before overwriting with Q
    { PROJ4(fA, bc); ST4(myQ, 0); }
    ENDSTEP();
    // s1: WQ h1
    ISSUE(WKT, 128);
    { PROJ4(fA, bc); ST4(myQ, 4); }
    ENDSTEP();
    // s2: WK h0
    ISSUE(WKT + 8192, 128);
    { PROJ4(fA, bc); ST4(myK, 0); }
    ENDSTEP();
    // s3: WK h1
    ISSUE(WVT, 128);
    { PROJ4(fA, bc); ST4(myK, 4); }
    ENDSTEP();
    // s4: WV h0
    f32x4 vacc[8];
    ISSUE(WVT + 8192, 128);
    { PROJ4(fA, bc); vacc[0] = g0; vacc[1] = g1; vacc[2] = g2; vacc[3] = g3; }
    ENDSTEP();
    // s5: WV h1 + attention (AF h0 flies underneath)
    ISSUE(AFT, 128);
    { PROJ4(fA, bc); vacc[4] = g0; vacc[5] = g1; vacc[6] = g2; vacc[7] = g3; }
    {
      // S^T for all heads (reads myQ=Q, myK=K)
      f32x4 st[8];
      #pragma unroll
      for (int h = 0; h < 8; ++h) {
        bf16x8 ka = B0, qa = B0;
        if (lq < 2) {
          ka = tile_ld8(myK, li, h * 16 + lq * 8);
          qa = tile_ld8(myQ, li, h * 16 + lq * 8);
        }
        st[h] = mfma16(ka, qa, F0);  // row k=lq*4+r, col q=li
      }
      LDS_FENCE();                   // Q,K reads complete before overlays
      // K dead -> Vt := myK  ([dv=128][k=16], b64 packed)
      #pragma unroll
      for (int c = 0; c < 8; ++c) {
        bf16x4 pkv;
        #pragma unroll
        for (int r = 0; r < 4; ++r) pkv[r] = f2bf(vacc[c][r]);
        *(bf16x4*)(myK + (c * 16 + li) * 16 + lq * 4) = pkv;
      }
      LDS_FENCE();                   // Vt visible before PV reads
      // softmax + PV per head; Q dead -> Os := myQ
      #pragma unroll
      for (int h = 0; h < 8; ++h) {
        float p[4]; float mx = -1e30f;
        #pragma unroll
        for (int r = 0; r < 4; ++r) { p[r] = st[h][r] * 0.25f; mx = fmaxf(mx, p[r]); }
        mx = fmaxf(mx, __shfl_xor(mx, 16, 64));
        mx = fmaxf(mx, __shfl_xor(mx, 32, 64));
        float sum = 0.f;
        #pragma unroll
        for (int r = 0; r < 4; ++r) { p[r] = __expf(p[r] - mx); sum += p[r]; }
        sum += __shfl_xor(sum, 16, 64);
        sum += __shfl_xor(sum, 32, 64);
        float inv = 1.0f / sum;
        #pragma unroll
        for (int r = 0; r < 4; ++r) p[r] *= inv;
        bf16x8 pa;
        #pragma unroll
        for (int j = 0; j < 8; ++j) {
          float v = __shfl(p[j & 3], li + 16 * (2 * lq + (j >> 2)), 64);
          pa[j] = (lq < 2) ? f2bf(v) : (short)0;
        }
        bf16x8 vb = B0;
        if (lq < 2) vb = *(const bf16x8*)(myK + (h * 16 + li) * 16 + lq * 8);
        f32x4 o = mfma16(pa, vb, F0);  // O: row q=lq*4+r, col dv=li
        #pragma unroll
        for (int r = 0; r < 4; ++r)
          tile_st16(myQ, lq * 4 + r, h * 16 + li, f2bf(o[r]));
      }
      LDS_FENCE();                   // Os stores complete before oa loads
    }
    bf16x8 oa[4];
    #pragma unroll
    for (int s = 0; s < 4; ++s) oa[s] = tile_ld8(myQ, li, s * 32 + lq * 8);
    ENDSTEP();
    // s6: AF h0
    ISSUE(AFT + 8192, 128);
    #pragma unroll
    for (int j = 0; j < 4; ++j) {
      float b = attn_fc_b[il * 128 + j * 16 + li];
      #pragma unroll
      for (int r = 0; r < 4; ++r) acc[j][r] += b;   // C-in: f + bias
    }
    ACC4(oa, 0, bc);
    ENDSTEP();
    // s7: AF h1 + LN
    ISSUE(W1T, 128);
    #pragma unroll
    for (int j = 0; j < 4; ++j) {
      float b = attn_fc_b[il * 128 + (4 + j) * 16 + li];
      #pragma unroll
      for (int r = 0; r < 4; ++r) acc[4 + j][r] += b;
    }
    ACC4(oa, 4, bc);
    LAYER_NORM(acc, attn_ln_g + il * 128, attn_ln_b + il * 128);
    ST_TILE(myQ, acc);
    LD_FA(myQ);
    #pragma unroll
    for (int c = 0; c < 8; ++c) {
      float b2 = ffn_b2[il * 128 + c * 16 + li];
      #pragma unroll
      for (int r = 0; r < 4; ++r) acc[c][r] += b2;  // C-in: f' + b2
    }
    ENDSTEP();

    // FFN col-tiles
    for (int ct = 0; ct < 4; ++ct) {
      const short* W1c = W1T + ct * 16384;
      const short* W2c = W2T + ct * 128;
      const float* b1p = ffn_b1 + il * 512 + ct * 128;
      // W1 h0
      ISSUE(W1c + 8192, 128);
      {
        PROJ4(fA, bc);
        float b10 = b1p[0 * 16 + li], b11 = b1p[1 * 16 + li];
        float b12 = b1p[2 * 16 + li], b13 = b1p[3 * 16 + li];
        #pragma unroll
        for (int r = 0; r < 4; ++r) {
          tile_st16(myK, lq * 4 + r, 0 * 16 + li, f2bf(fmaxf(g0[r] + b10, 0.f)));
          tile_st16(myK, lq * 4 + r, 1 * 16 + li, f2bf(fmaxf(g1[r] + b11, 0.f)));
          tile_st16(myK, lq * 4 + r, 2 * 16 + li, f2bf(fmaxf(g2[r] + b12, 0.f)));
          tile_st16(myK, lq * 4 + r, 3 * 16 + li, f2bf(fmaxf(g3[r] + b13, 0.f)));
        }
      }
      ENDSTEP();
      // W1 h1
      ISSUE(W2c, 512);
      {
        PROJ4(fA, bc);
        float b14 = b1p[4 * 16 + li], b15 = b1p[5 * 16 + li];
        float b16 = b1p[6 * 16 + li], b17 = b1p[7 * 16 + li];
        #pragma unroll
        for (int r = 0; r < 4; ++r) {
          tile_st16(myK, lq * 4 + r, 4 * 16 + li, f2bf(fmaxf(g0[r] + b14, 0.f)));
          tile_st16(myK, lq * 4 + r, 5 * 16 + li, f2bf(fmaxf(g1[r] + b15, 0.f)));
          tile_st16(myK, lq * 4 + r, 6 * 16 + li, f2bf(fmaxf(g2[r] + b16, 0.f)));
          tile_st16(myK, lq * 4 + r, 7 * 16 + li, f2bf(fmaxf(g3[r] + b17, 0.f)));
        }
      }
      LDS_FENCE();
      bf16x8 ha[4];
      #pragma unroll
      for (int s = 0; s < 4; ++s) ha[s] = tile_ld8(myK, li, s * 32 + lq * 8);
      ENDSTEP();
      // W2 h0
      ISSUE(W2c + 64 * 512, 512);
      ACC4(ha, 0, bc);
      ENDSTEP();
      // W2 h1
      {
        const short* nx = (ct < 3) ? (W1T + (ct + 1) * 16384) : WQN;
        ISSUE(nx, 128);
      }
      ACC4(ha, 4, bc);
      if (ct == 3) {
        LAYER_NORM(acc, ffn_ln_g + il * 128, ffn_ln_b + il * 128);
        ST_TILE(myQ, acc);   // f for next layer
      }
      ENDSTEP();
    }
  }

  // ================= pooling + fea2node + final LN =================
  float pc[8];
  #pragma unroll
  for (int c = 0; c < 8; ++c) {
    float s = acc[c][0] + acc[c][1] + acc[c][2] + acc[c][3];
    s += __shfl_xor(s, 16, 64);
    s += __shfl_xor(s, 32, 64);
    pc[c] = s * (1.f / 16.f);
  }
  float* ps = (float*)myK;  // 128 floats scratch (wave-private)
  if (lq == 0) {
    #pragma unroll
    for (int c = 0; c < 8; ++c) ps[c * 16 + li] = pc[c];
  }
  LDS_FENCE();
  const short* F2NT = wsb + OFF_F2N;
  float yv[2];
  #pragma unroll
  for (int half = 0; half < 2; ++half) {
    int col = half * 64 + lane;
    float dot = 0.f;
    for (int d0 = 0; d0 < 128; d0 += 8) {
      bf16x8 wv8 = *(const bf16x8*)(F2NT + col * 128 + d0);
      f32x4 p0 = *(const f32x4*)(ps + d0);
      f32x4 p1 = *(const f32x4*)(ps + d0 + 4);
      dot += p0[0] * bf2f(wv8[0]) + p0[1] * bf2f(wv8[1]) + p0[2] * bf2f(wv8[2]) + p0[3] * bf2f(wv8[3]);
      dot += p1[0] * bf2f(wv8[4]) + p1[1] * bf2f(wv8[5]) + p1[2] * bf2f(wv8[6]) + p1[3] * bf2f(wv8[7]);
    }
    yv[half] = gelu_f(dot + f2n_b[col]) + node_h[(size_t)n * 128 + col];
  }
  float s1 = yv[0] + yv[1], s2 = yv[0] * yv[0] + yv[1] * yv[1];
  #pragma unroll
  for (int m = 1; m <= 32; m <<= 1) { s1 += __shfl_xor(s1, m, 64); s2 += __shfl_xor(s2, m, 64); }
  float mean = s1 * (1.f / 128.f);
  float var = s2 * (1.f / 128.f) - mean * mean;
  float rstd = rsqrtf(var + 1e-5f);
  #pragma unroll
  for (int half = 0; half < 2; ++half) {
    int col = half * 64 + lane;
    out[(size_t)n * 128 + col] = (yv[half] - mean) * rstd * fin_g[col] + fin_b[col];
  }
}

extern "C" void kernel_launch(void* const* d_in, const int* in_sizes, int n_in,
                              void* d_out, int out_size, void* d_ws, size_t ws_size,
                              hipStream_t stream) {
  const float* node_h    = (const float*)d_in[0];
  const int*   src_idx   = (const int*)d_in[1];
  const float* edge_feat = (const float*)d_in[2];
  const float* t_arr     = (const float*)d_in[3];
  const float* t_now     = (const float*)d_in[4];
  const float* edge_fc_w = (const float*)d_in[5];
  const float* edge_fc_b = (const float*)d_in[6];
  const float* basis_frq = (const float*)d_in[7];
  const float* phase     = (const float*)d_in[8];
  const float* wq        = (const float*)d_in[9];
  const float* wk        = (const float*)d_in[10];
  const float* wv        = (const float*)d_in[11];
  const float* attn_fc_w = (const float*)d_in[12];
  const float* attn_fc_b = (const float*)d_in[13];
  const float* attn_ln_g = (const float*)d_in[14];
  const float* attn_ln_b = (const float*)d_in[15];
  const float* ffn_w1    = (const float*)d_in[16];
  const float* ffn_b1    = (const float*)d_in[17];
  const float* ffn_w2    = (const float*)d_in[18];
  const float* ffn_b2    = (const float*)d_in[19];
  const float* ffn_ln_g  = (const float*)d_in[20];
  const float* ffn_ln_b  = (const float*)d_in[21];
  const float* f2n_w     = (const float*)d_in[22];
  const float* f2n_b     = (const float*)d_in[23];
  const float* fin_g     = (const float*)d_in[24];
  const float* fin_b     = (const float*)d_in[25];
  short* wsb = (short*)d_ws;

  prep_kernel<<<(TOTAL_W + 255) / 256, 256, 0, stream>>>(
      edge_fc_w, wq, wk, wv, attn_fc_w, ffn_w1, ffn_w2, f2n_w, wsb);
  fused_kernel<<<NN / 4, 256, 0, stream>>>(
      node_h, src_idx, edge_feat, t_arr, t_now, edge_fc_b, basis_frq, phase,
      attn_fc_b, attn_ln_g, attn_ln_b, ffn_b1, ffn_b2, ffn_ln_g, ffn_ln_b,
      f2n_b, fin_g, fin_b, wsb, (float*)d_out);
}

// Round 7
// 689.722 us; speedup vs baseline: 1.3341x; 1.0993x over previous
//
#include <hip/hip_runtime.h>

// Problem constants
#define NN 16384
// ws (bf16) region offsets, in elements
#define OFF_EWT 0
#define OFF_WQT 4096
#define OFF_WKT 36864
#define OFF_WVT 69632
#define OFF_AFT 102400
#define OFF_W1T 135168
#define OFF_W2T 266240
#define OFF_F2N 397312
#define TOTAL_W 413696

typedef __attribute__((ext_vector_type(8))) short bf16x8;
typedef __attribute__((ext_vector_type(4))) short bf16x4;
typedef __attribute__((ext_vector_type(4))) float f32x4;

static __device__ __forceinline__ short f2bf(float f) {
  unsigned u = __builtin_bit_cast(unsigned, f);
  u += 0x7fffu + ((u >> 16) & 1u);           // RNE
  return (short)(u >> 16);
}
static __device__ __forceinline__ float bf2f(short h) {
  unsigned u = ((unsigned)(unsigned short)h) << 16;
  return __builtin_bit_cast(float, u);
}
static __device__ __forceinline__ float gelu_f(float x) {
  float e = __expf(1.5957691216057308f * (x + 0.044715f * x * x * x));
  return x - x / (e + 1.0f);
}
static __device__ __forceinline__ f32x4 mfma16(bf16x8 a, bf16x8 b, f32x4 c) {
  return __builtin_amdgcn_mfma_f32_16x16x32_bf16(a, b, c, 0, 0, 0);
}
// XOR bank swizzle
#define SWZM(row) (((((row) & 7) << 4)) ^ ((((row) >> 3) & 3) << 5))
static __device__ __forceinline__ int swzb(int row, int col) {
  return row * 256 + ((col * 2) ^ SWZM(row));
}
static __device__ __forceinline__ bf16x8 tile_ld8(const short* base, int row, int col) {
  return *(const bf16x8*)((const char*)base + swzb(row, col));
}
static __device__ __forceinline__ void tile_st16(short* base, int row, int col, short v) {
  *(short*)((char*)base + swzb(row, col)) = v;
}
// async quarter-stage: 32 rows x 128 cols bf16 (8KB) -> swizzled LDS buffer.
static __device__ __forceinline__ void stage_w(short* dst, const short* src, int stride,
                                               int w, int lane) {
  #pragma unroll
  for (int it = 0; it < 2; ++it) {
    int dbase = (it * 4 + w) * 1024;
    int d = dbase + lane * 16;
    int row = d >> 8;                         // 0..31 local row
    int scolb = (d & 255) ^ SWZM(row);        // source byte-in-row (involution)
    const short* sp = src + row * stride + (scolb >> 1);
    __builtin_amdgcn_global_load_lds(
        (const __attribute__((address_space(1))) unsigned int*)sp,
        (__attribute__((address_space(3))) unsigned int*)((char*)dst + dbase),
        16, 0, 0);
  }
}

#define LDS_FENCE() do {                                       \
    asm volatile("s_waitcnt lgkmcnt(0)" ::: "memory");         \
    __builtin_amdgcn_sched_barrier(0);                         \
  } while (0)

#define ISSUE(SRC, STRIDE) stage_w(bn, (SRC), (STRIDE), w, lane)
#define ENDSTEP() do {                                         \
    __syncthreads();                                           \
    short* _t = bc; bc = bn; bn = _t;                          \
  } while (0)

#define LD_FA2() do {                                                     \
    _Pragma("unroll") for (int _s = 0; _s < 4; ++_s) {                    \
      fA0[_s] = tile_ld8(myQ0, li, _s * 32 + lq * 8);                     \
      fA1[_s] = tile_ld8(myQ1, li, _s * 32 + lq * 8);                     \
    }                                                                     \
  } while (0)

#define ST_TILE(T, ACC)                                                   \
  _Pragma("unroll") for (int _c = 0; _c < 8; ++_c)                        \
    _Pragma("unroll") for (int _r = 0; _r < 4; ++_r)                      \
      tile_st16((T), lq * 4 + _r, _c * 16 + li, f2bf((ACC)[_c][_r]));

// dual-node quarter projection: 8 B-frag reads feed 16 MFMAs
#define PROJ2D(BB)                                                        \
    f32x4 ga0 = F0, ga1 = F0, gb0 = F0, gb1 = F0;                         \
    _Pragma("unroll") for (int _s = 0; _s < 4; ++_s) {                    \
      int _sc = _s * 32 + lq * 8;                                         \
      bf16x8 _b0 = tile_ld8((BB), 0 + li, _sc);                           \
      bf16x8 _b1 = tile_ld8((BB), 16 + li, _sc);                          \
      ga0 = mfma16(fA0[_s], _b0, ga0); gb0 = mfma16(fA1[_s], _b0, gb0);   \
      ga1 = mfma16(fA0[_s], _b1, ga1); gb1 = mfma16(fA1[_s], _b1, gb1);   \
    }

#define ST2D(D0, D1, CB)                                                  \
    _Pragma("unroll") for (int _r = 0; _r < 4; ++_r) {                    \
      tile_st16((D0), lq * 4 + _r, (CB) * 16 + li, f2bf(ga0[_r]));        \
      tile_st16((D0), lq * 4 + _r, ((CB) + 1) * 16 + li, f2bf(ga1[_r]));  \
      tile_st16((D1), lq * 4 + _r, (CB) * 16 + li, f2bf(gb0[_r]));        \
      tile_st16((D1), lq * 4 + _r, ((CB) + 1) * 16 + li, f2bf(gb1[_r]));  \
    }

// dual-node quarter accumulate: acc{0,1}[CB..CB+1] += A{0,1} * staged quarter
#define ACC2D(AR0, AR1, CB, BB)                                           \
    _Pragma("unroll") for (int _s = 0; _s < 4; ++_s) {                    \
      int _sc = _s * 32 + lq * 8;                                         \
      bf16x8 _b0 = tile_ld8((BB), 0 + li, _sc);                           \
      bf16x8 _b1 = tile_ld8((BB), 16 + li, _sc);                          \
      acc0[(CB)] = mfma16(AR0[_s], _b0, acc0[(CB)]);                      \
      acc1[(CB)] = mfma16(AR1[_s], _b0, acc1[(CB)]);                      \
      acc0[(CB) + 1] = mfma16(AR0[_s], _b1, acc0[(CB) + 1]);              \
      acc1[(CB) + 1] = mfma16(AR1[_s], _b1, acc1[(CB) + 1]);              \
    }

#define LAYER_NORM(A, GP, BP) do {                                        \
    float _gg[8], _bb[8];                                                 \
    _Pragma("unroll") for (int _c = 0; _c < 8; ++_c) {                    \
      _gg[_c] = (GP)[_c * 16 + li]; _bb[_c] = (BP)[_c * 16 + li]; }       \
    _Pragma("unroll") for (int _r = 0; _r < 4; ++_r) {                    \
      float _s1 = 0.f, _s2 = 0.f;                                         \
      _Pragma("unroll") for (int _c = 0; _c < 8; ++_c) {                  \
        float _v = (A)[_c][_r]; _s1 += _v; _s2 += _v * _v; }              \
      _Pragma("unroll") for (int _m = 1; _m <= 8; _m <<= 1) {             \
        _s1 += __shfl_xor(_s1, _m, 64); _s2 += __shfl_xor(_s2, _m, 64); } \
      float _mean = _s1 * (1.f / 128.f);                                  \
      float _var = _s2 * (1.f / 128.f) - _mean * _mean;                   \
      float _rstd = rsqrtf(_var + 1e-5f);                                 \
      _Pragma("unroll") for (int _c = 0; _c < 8; ++_c)                    \
        (A)[_c][_r] = ((A)[_c][_r] - _mean) * _rstd * _gg[_c] + _bb[_c];  \
    }                                                                     \
  } while (0)

// wave-private attention for one node; overlays Vt->MYK, Os->MYQ (both dead)
#define ATTN(MYQ, MYK, VACC, OA) do {                                     \
    f32x4 _st[8];                                                         \
    _Pragma("unroll") for (int _h = 0; _h < 8; ++_h) {                    \
      bf16x8 _ka = B0, _qa = B0;                                          \
      if (lq < 2) {                                                       \
        _ka = tile_ld8((MYK), li, _h * 16 + lq * 8);                      \
        _qa = tile_ld8((MYQ), li, _h * 16 + lq * 8);                      \
      }                                                                   \
      _st[_h] = mfma16(_ka, _qa, F0);                                     \
    }                                                                     \
    LDS_FENCE();                                                          \
    _Pragma("unroll") for (int _c = 0; _c < 8; ++_c) {                    \
      bf16x4 _pk;                                                         \
      _Pragma("unroll") for (int _r = 0; _r < 4; ++_r)                    \
        _pk[_r] = f2bf((VACC)[_c][_r]);                                   \
      *(bf16x4*)((MYK) + (_c * 16 + li) * 16 + lq * 4) = _pk;             \
    }                                                                     \
    LDS_FENCE();                                                          \
    _Pragma("unroll") for (int _h = 0; _h < 8; ++_h) {                    \
      float _p[4]; float _mx = -1e30f;                                    \
      _Pragma("unroll") for (int _r = 0; _r < 4; ++_r) {                  \
        _p[_r] = _st[_h][_r] * 0.25f; _mx = fmaxf(_mx, _p[_r]); }         \
      _mx = fmaxf(_mx, __shfl_xor(_mx, 16, 64));                          \
      _mx = fmaxf(_mx, __shfl_xor(_mx, 32, 64));                          \
      float _sum = 0.f;                                                   \
      _Pragma("unroll") for (int _r = 0; _r < 4; ++_r) {                  \
        _p[_r] = __expf(_p[_r] - _mx); _sum += _p[_r]; }                  \
      _sum += __shfl_xor(_sum, 16, 64);                                   \
      _sum += __shfl_xor(_sum, 32, 64);                                   \
      float _inv = 1.0f / _sum;                                           \
      _Pragma("unroll") for (int _r = 0; _r < 4; ++_r) _p[_r] *= _inv;    \
      bf16x8 _pa;                                                         \
      _Pragma("unroll") for (int _j = 0; _j < 8; ++_j) {                  \
        float _v = __shfl(_p[_j & 3], li + 16 * (2 * lq + (_j >> 2)), 64);\
        _pa[_j] = (lq < 2) ? f2bf(_v) : (short)0;                         \
      }                                                                   \
      bf16x8 _vb = B0;                                                    \
      if (lq < 2) _vb = *(const bf16x8*)((MYK) + (_h * 16 + li) * 16 + lq * 8); \
      f32x4 _o = mfma16(_pa, _vb, F0);                                    \
      _Pragma("unroll") for (int _r = 0; _r < 4; ++_r)                    \
        tile_st16((MYQ), lq * 4 + _r, _h * 16 + li, f2bf(_o[_r]));        \
    }                                                                     \
    LDS_FENCE();                                                          \
    _Pragma("unroll") for (int _s = 0; _s < 4; ++_s)                      \
      (OA)[_s] = tile_ld8((MYQ), li, _s * 32 + lq * 8);                   \
  } while (0)

// ---- prep: transpose + fp32->bf16 all weight matrices into ws ----
__global__ void prep_kernel(const float* __restrict__ ew, const float* __restrict__ wq,
                            const float* __restrict__ wk, const float* __restrict__ wv,
                            const float* __restrict__ afc, const float* __restrict__ w1,
                            const float* __restrict__ w2, const float* __restrict__ f2n,
                            short* __restrict__ wsb) {
  int tt = blockIdx.x * 256 + threadIdx.x;
  if (tt >= TOTAL_W) return;
  short v;
  if (tt < OFF_WQT) {                       // EWT [128][32] <- ew [32][128]
    int u = tt; int row = u >> 5, colr = u & 31;
    v = f2bf(ew[colr * 128 + row]);
  } else if (tt < OFF_WKT) {                // WQT [2][128][128]
    int u = tt - OFF_WQT; int i = u >> 14; u &= 16383; int row = u >> 7, colr = u & 127;
    v = f2bf(wq[i * 16384 + colr * 128 + row]);
  } else if (tt < OFF_WVT) {
    int u = tt - OFF_WKT; int i = u >> 14; u &= 16383; int row = u >> 7, colr = u & 127;
    v = f2bf(wk[i * 16384 + colr * 128 + row]);
  } else if (tt < OFF_AFT) {
    int u = tt - OFF_WVT; int i = u >> 14; u &= 16383; int row = u >> 7, colr = u & 127;
    v = f2bf(wv[i * 16384 + colr * 128 + row]);
  } else if (tt < OFF_W1T) {                // AFT [2][128][128]
    int u = tt - OFF_AFT; int i = u >> 14; u &= 16383; int row = u >> 7, colr = u & 127;
    v = f2bf(afc[i * 16384 + colr * 128 + row]);
  } else if (tt < OFF_W2T) {                // W1T [2][512][128] <- w1 [2][128][512]
    int u = tt - OFF_W1T; int i = u >> 16; u &= 65535; int row = u >> 7, colr = u & 127;
    v = f2bf(w1[i * 65536 + colr * 512 + row]);
  } else if (tt < OFF_F2N) {                // W2T [2][128][512] <- w2 [2][512][128]
    int u = tt - OFF_W2T; int i = u >> 16; u &= 65535; int row = u >> 9, colr = u & 511;
    v = f2bf(w2[i * 65536 + colr * 128 + row]);
  } else {                                  // F2N [128][128] <- f2n [128][128]
    int u = tt - OFF_F2N; int row = u >> 7, colr = u & 127;
    v = f2bf(f2n[colr * 128 + row]);
  }
  wsb[tt] = v;
}

// ---- fused main kernel: 1 wave = 2 nodes, 4 waves/WG, quarter-tile dbuf ----
__global__ __launch_bounds__(256, 2) void fused_kernel(
    const float* __restrict__ node_h, const int* __restrict__ src_idx,
    const float* __restrict__ edge_feat, const float* __restrict__ t_arr,
    const float* __restrict__ t_now, const float* __restrict__ edge_fc_b,
    const float* __restrict__ basis_freq, const float* __restrict__ phase,
    const float* __restrict__ attn_fc_b, const float* __restrict__ attn_ln_g,
    const float* __restrict__ attn_ln_b, const float* __restrict__ ffn_b1,
    const float* __restrict__ ffn_b2, const float* __restrict__ ffn_ln_g,
    const float* __restrict__ ffn_ln_b, const float* __restrict__ f2n_b,
    const float* __restrict__ fin_g, const float* __restrict__ fin_b,
    const short* __restrict__ wsb, float* __restrict__ out) {
  __shared__ __align__(16) short bufs0[4096];      // 8KB weight quarter A
  __shared__ __align__(16) short bufs1[4096];      // 8KB weight quarter B
  __shared__ __align__(16) short lds_qk[4][8192];  // per-wave Q0,K0,Q1,K1 tiles

  const int tid = (int)threadIdx.x;
  const int w = tid >> 6, lane = tid & 63, li = lane & 15, lq = lane >> 4;
  const int n0 = (int)blockIdx.x * 8 + w * 2;
  const int n1 = n0 + 1;
  short* myQ0 = lds_qk[w];
  short* myK0 = lds_qk[w] + 2048;
  short* myQ1 = lds_qk[w] + 4096;
  short* myK1 = lds_qk[w] + 6144;
  short* bc = bufs0;
  short* bn = bufs1;
  const f32x4 F0 = {0.f, 0.f, 0.f, 0.f};
  const bf16x8 B0 = {0, 0, 0, 0, 0, 0, 0, 0};

  // prologue: issue layer-0 WQ q0 before the message phase
  stage_w(bc, wsb + OFF_WQT, 128, w, lane);

  const float tnow = t_now[0];

  f32x4 acc0[8], acc1[8];
  // ================= message phase (both nodes) =================
  {
    const short* ewt = wsb + OFF_EWT;
    const float* ef0 = edge_feat + ((size_t)(n0 * 16 + li)) * 32 + lq * 8;
    const float* ef1 = edge_feat + ((size_t)(n1 * 16 + li)) * 32 + lq * 8;
    f32x4 ea0 = *(const f32x4*)(ef0), ea0b = *(const f32x4*)(ef0 + 4);
    f32x4 ea1 = *(const f32x4*)(ef1), ea1b = *(const f32x4*)(ef1 + 4);
    bf16x8 e0, e1;
    #pragma unroll
    for (int j = 0; j < 4; ++j) {
      e0[j] = f2bf(ea0[j]); e0[j + 4] = f2bf(ea0b[j]);
      e1[j] = f2bf(ea1[j]); e1[j + 4] = f2bf(ea1b[j]);
    }
    #pragma unroll
    for (int c = 0; c < 8; ++c) {
      bf16x8 eb = *(const bf16x8*)(ewt + (c * 16 + li) * 32 + lq * 8);
      acc0[c] = mfma16(e0, eb, F0);
      acc1[c] = mfma16(e1, eb, F0);
    }
  }
  {
    float bfq[8], phs[8], ebs[8];
    #pragma unroll
    for (int c = 0; c < 8; ++c) {
      int col = c * 16 + li;
      bfq[c] = basis_freq[col]; phs[c] = phase[col]; ebs[c] = edge_fc_b[col];
    }
    #pragma unroll
    for (int r = 0; r < 4; ++r) {
      int m = lq * 4 + r;
      int s0 = src_idx[n0 * 16 + m], s1 = src_idx[n1 * 16 + m];
      float dt0 = tnow - t_arr[n0 * 16 + m], dt1 = tnow - t_arr[n1 * 16 + m];
      const float* nh0 = node_h + (size_t)s0 * 128;
      const float* nh1 = node_h + (size_t)s1 * 128;
      #pragma unroll
      for (int c = 0; c < 8; ++c) {
        int col = c * 16 + li;
        acc0[c][r] = gelu_f(acc0[c][r] + ebs[c]) + nh0[col] + __cosf(dt0 * bfq[c] + phs[c]);
        acc1[c][r] = gelu_f(acc1[c][r] + ebs[c]) + nh1[col] + __cosf(dt1 * bfq[c] + phs[c]);
      }
    }
  }
  ST_TILE(myQ0, acc0);
  ST_TILE(myQ1, acc1);
  __syncthreads();     // f tiles ready; prologue stage drained

  bf16x8 fA0[4], fA1[4];
  bf16x8 oa0_[4], oa1_[4];
  bf16x8 ha0_[4], ha1_[4];

  // ================= transformer layers (48 quarter-steps each) =================
  for (int il = 0; il < 2; ++il) {
    const short* WQT = wsb + OFF_WQT + il * 16384;
    const short* WKT = wsb + OFF_WKT + il * 16384;
    const short* WVT = wsb + OFF_WVT + il * 16384;
    const short* AFT = wsb + OFF_AFT + il * 16384;
    const short* W1T = wsb + OFF_W1T + il * 65536;
    const short* W2T = wsb + OFF_W2T + il * 65536;
    const short* WQN = wsb + OFF_WQT + ((il == 0) ? 16384 : 0);  // dummy on last

    f32x4 vacc0[8], vacc1[8];

    // ---- WQ quarters ----
    #pragma unroll
    for (int q = 0; q < 4; ++q) {
      const short* nx = (q < 3) ? (WQT + (q + 1) * 4096) : WKT;
      ISSUE(nx, 128);
      if (q == 0) LD_FA2();   // read f before Q overwrites
      { PROJ2D(bc); ST2D(myQ0, myQ1, q * 2); }
      ENDSTEP();
    }
    // ---- WK quarters ----
    #pragma unroll
    for (int q = 0; q < 4; ++q) {
      const short* nx = (q < 3) ? (WKT + (q + 1) * 4096) : WVT;
      ISSUE(nx, 128);
      { PROJ2D(bc); ST2D(myK0, myK1, q * 2); }
      ENDSTEP();
    }
    // ---- WV quarters (+ attention at q3) ----
    #pragma unroll
    for (int q = 0; q < 4; ++q) {
      const short* nx = (q < 3) ? (WVT + (q + 1) * 4096) : AFT;
      ISSUE(nx, 128);
      {
        PROJ2D(bc);
        vacc0[q * 2] = ga0; vacc0[q * 2 + 1] = ga1;
        vacc1[q * 2] = gb0; vacc1[q * 2 + 1] = gb1;
      }
      if (q == 3) {
        ATTN(myQ0, myK0, vacc0, oa0_);
        ATTN(myQ1, myK1, vacc1, oa1_);
      }
      ENDSTEP();
    }
    // ---- AF quarters ----
    #pragma unroll
    for (int q = 0; q < 4; ++q) {
      const short* nx = (q < 3) ? (AFT + (q + 1) * 4096) : W1T;
      ISSUE(nx, 128);
      #pragma unroll
      for (int j = 0; j < 2; ++j) {
        float b = attn_fc_b[il * 128 + (q * 2 + j) * 16 + li];
        #pragma unroll
        for (int r = 0; r < 4; ++r) { acc0[q * 2 + j][r] += b; acc1[q * 2 + j][r] += b; }
      }
      ACC2D(oa0_, oa1_, q * 2, bc);
      if (q == 3) {
        LAYER_NORM(acc0, attn_ln_g + il * 128, attn_ln_b + il * 128);
        LAYER_NORM(acc1, attn_ln_g + il * 128, attn_ln_b + il * 128);
        ST_TILE(myQ0, acc0);
        ST_TILE(myQ1, acc1);
        LD_FA2();
        #pragma unroll
        for (int c = 0; c < 8; ++c) {
          float b2 = ffn_b2[il * 128 + c * 16 + li];
          #pragma unroll
          for (int r = 0; r < 4; ++r) { acc0[c][r] += b2; acc1[c][r] += b2; }
        }
      }
      ENDSTEP();
    }

    // ---- FFN col-tiles ----
    for (int ct = 0; ct < 4; ++ct) {
      const short* W1c = W1T + ct * 16384;                  // rows ct*128.., stride 128
      const short* W2c = W2T + ct * 128;                    // cols ct*128.., stride 512
      const float* b1p = ffn_b1 + il * 512 + ct * 128;
      // W1 quarters -> hid tiles (myK overlays)
      #pragma unroll
      for (int q = 0; q < 4; ++q) {
        const short* nx = (q < 3) ? (W1c + (q + 1) * 4096) : W2c;
        ISSUE(nx, (q < 3) ? 128 : 512);
        {
          PROJ2D(bc);
          float ba = b1p[(q * 2) * 16 + li], bb = b1p[(q * 2 + 1) * 16 + li];
          #pragma unroll
          for (int r = 0; r < 4; ++r) {
            tile_st16(myK0, lq * 4 + r, (q * 2) * 16 + li, f2bf(fmaxf(ga0[r] + ba, 0.f)));
            tile_st16(myK0, lq * 4 + r, (q * 2 + 1) * 16 + li, f2bf(fmaxf(ga1[r] + bb, 0.f)));
            tile_st16(myK1, lq * 4 + r, (q * 2) * 16 + li, f2bf(fmaxf(gb0[r] + ba, 0.f)));
            tile_st16(myK1, lq * 4 + r, (q * 2 + 1) * 16 + li, f2bf(fmaxf(gb1[r] + bb, 0.f)));
          }
        }
        if (q == 3) {
          LDS_FENCE();
          #pragma unroll
          for (int s = 0; s < 4; ++s) {
            ha0_[s] = tile_ld8(myK0, li, s * 32 + lq * 8);
            ha1_[s] = tile_ld8(myK1, li, s * 32 + lq * 8);
          }
        }
        ENDSTEP();
      }
      // W2 quarters (out-col groups of 32)
      #pragma unroll
      for (int q = 0; q < 4; ++q) {
        const short* nx;
        int nstr;
        if (q < 3) { nx = W2c + (q + 1) * 32 * 512; nstr = 512; }
        else if (ct < 3) { nx = W1T + (ct + 1) * 16384; nstr = 128; }
        else { nx = WQN; nstr = 128; }
        ISSUE(nx, nstr);
        ACC2D(ha0_, ha1_, q * 2, bc);
        if (ct == 3 && q == 3) {
          LAYER_NORM(acc0, ffn_ln_g + il * 128, ffn_ln_b + il * 128);
          LAYER_NORM(acc1, ffn_ln_g + il * 128, ffn_ln_b + il * 128);
          ST_TILE(myQ0, acc0);
          ST_TILE(myQ1, acc1);
        }
        ENDSTEP();
      }
    }
  }
  asm volatile("s_waitcnt vmcnt(0)" ::: "memory");

  // ================= pooling + fea2node + final LN (both nodes) =================
  {
    float pc0[8], pc1[8];
    #pragma unroll
    for (int c = 0; c < 8; ++c) {
      float s0 = acc0[c][0] + acc0[c][1] + acc0[c][2] + acc0[c][3];
      float s1 = acc1[c][0] + acc1[c][1] + acc1[c][2] + acc1[c][3];
      s0 += __shfl_xor(s0, 16, 64); s0 += __shfl_xor(s0, 32, 64);
      s1 += __shfl_xor(s1, 16, 64); s1 += __shfl_xor(s1, 32, 64);
      pc0[c] = s0 * (1.f / 16.f);
      pc1[c] = s1 * (1.f / 16.f);
    }
    float* ps0 = (float*)myK0;
    float* ps1 = (float*)myK1;
    if (lq == 0) {
      #pragma unroll
      for (int c = 0; c < 8; ++c) { ps0[c * 16 + li] = pc0[c]; ps1[c * 16 + li] = pc1[c]; }
    }
    LDS_FENCE();
    const short* F2NT = wsb + OFF_F2N;
    #pragma unroll
    for (int nd = 0; nd < 2; ++nd) {
      const float* ps = nd ? ps1 : ps0;      // LDS pointer select (compile-time unrolled)
      int n = nd ? n1 : n0;
      float yv[2];
      #pragma unroll
      for (int half = 0; half < 2; ++half) {
        int col = half * 64 + lane;
        float dot = 0.f;
        for (int d0 = 0; d0 < 128; d0 += 8) {
          bf16x8 wv8 = *(const bf16x8*)(F2NT + col * 128 + d0);
          f32x4 p0 = *(const f32x4*)(ps + d0);
          f32x4 p1 = *(const f32x4*)(ps + d0 + 4);
          dot += p0[0] * bf2f(wv8[0]) + p0[1] * bf2f(wv8[1]) + p0[2] * bf2f(wv8[2]) + p0[3] * bf2f(wv8[3]);
          dot += p1[0] * bf2f(wv8[4]) + p1[1] * bf2f(wv8[5]) + p1[2] * bf2f(wv8[6]) + p1[3] * bf2f(wv8[7]);
        }
        yv[half] = gelu_f(dot + f2n_b[col]) + node_h[(size_t)n * 128 + col];
      }
      float s1v = yv[0] + yv[1], s2v = yv[0] * yv[0] + yv[1] * yv[1];
      #pragma unroll
      for (int m = 1; m <= 32; m <<= 1) {
        s1v += __shfl_xor(s1v, m, 64); s2v += __shfl_xor(s2v, m, 64);
      }
      float mean = s1v * (1.f / 128.f);
      float var = s2v * (1.f / 128.f) - mean * mean;
      float rstd = rsqrtf(var + 1e-5f);
      #pragma unroll
      for (int half = 0; half < 2; ++half) {
        int col = half * 64 + lane;
        out[(size_t)n * 128 + col] = (yv[half] - mean) * rstd * fin_g[col] + fin_b[col];
      }
    }
  }
}

extern "C" void kernel_launch(void* const* d_in, const int* in_sizes, int n_in,
                              void* d_out, int out_size, void* d_ws, size_t ws_size,
                              hipStream_t stream) {
  const float* node_h    = (const float*)d_in[0];
  const int*   src_idx   = (const int*)d_in[1];
  const float* edge_feat = (const float*)d_in[2];
  const float* t_arr     = (const float*)d_in[3];
  const float* t_now     = (const float*)d_in[4];
  const float* edge_fc_w = (const float*)d_in[5];
  const float* edge_fc_b = (const float*)d_in[6];
  const float* basis_frq = (const float*)d_in[7];
  const float* phase     = (const float*)d_in[8];
  const float* wq        = (const float*)d_in[9];
  const float* wk        = (const float*)d_in[10];
  const float* wv        = (const float*)d_in[11];
  const float* attn_fc_w = (const float*)d_in[12];
  const float* attn_fc_b = (const float*)d_in[13];
  const float* attn_ln_g = (const float*)d_in[14];
  const float* attn_ln_b = (const float*)d_in[15];
  const float* ffn_w1    = (const float*)d_in[16];
  const float* ffn_b1    = (const float*)d_in[17];
  const float* ffn_w2    = (const float*)d_in[18];
  const float* ffn_b2    = (const float*)d_in[19];
  const float* ffn_ln_g  = (const float*)d_in[20];
  const float* ffn_ln_b  = (const float*)d_in[21];
  const float* f2n_w     = (const float*)d_in[22];
  const float* f2n_b     = (const float*)d_in[23];
  const float* fin_g     = (const float*)d_in[24];
  const float* fin_b     = (const float*)d_in[25];
  short* wsb = (short*)d_ws;

  prep_kernel<<<(TOTAL_W + 255) / 256, 256, 0, stream>>>(
      edge_fc_w, wq, wk, wv, attn_fc_w, ffn_w1, ffn_w2, f2n_w, wsb);
  fused_kernel<<<NN / 8, 256, 0, stream>>>(
      node_h, src_idx, edge_feat, t_arr, t_now, edge_fc_b, basis_frq, phase,
      attn_fc_b, attn_ln_g, attn_ln_b, ffn_b1, ffn_b2, ffn_ln_g, ffn_ln_b,
      f2n_b, fin_g, fin_b, wsb, (float*)d_out);
}